// Round 1
// baseline (204.514 us; speedup 1.0000x reference)
//
#include <hip/hip_runtime.h>
#include <hip/hip_bf16.h>

// InfoNCE loss, N=4096, D=1024, TEMP=0.07.
// loss = mean_i( -pos_i + lse_i ), lse over sim rows with diagonal masked.
// Fixed-max LSE trick (rows unit-norm -> sim <= 1/T): partial sums are
// order-independent -> atomicAdd accumulation across tiles, upper-tri only.

typedef __attribute__((ext_vector_type(8))) short bf16x8;
typedef __attribute__((ext_vector_type(4))) float f32x4;
typedef __attribute__((ext_vector_type(8))) unsigned short u16x8;

#define NN 4096
#define TWO_N 8192
#define DIM 1024
#define TILE 128
#define BK 64
#define TEMP_INV 14.285714285714286f
#define EXP_SCALE 20.609929155566303f /* log2(e)/0.07 */

__device__ __forceinline__ unsigned short f2bf(float f) {
  unsigned int u = __float_as_uint(f);
  u += 0x7fffu + ((u >> 16) & 1u);  // RNE
  return (unsigned short)(u >> 16);
}

// fp32 -> bf16 cast of z = [z1; z2], vectorized 8 elems/thread.
__global__ __launch_bounds__(256) void convert_kernel(
    const float* __restrict__ z1, const float* __restrict__ z2,
    unsigned short* __restrict__ zb) {
  size_t i = (size_t)blockIdx.x * 256 + threadIdx.x;  // 1M threads x 8 elems
  const float* src = (i < (size_t)(NN * DIM / 8)) ? (z1 + i * 8)
                                                  : (z2 + i * 8 - (size_t)NN * DIM);
  float4 v0 = ((const float4*)src)[0];
  float4 v1 = ((const float4*)src)[1];
  u16x8 o;
  o[0] = f2bf(v0.x); o[1] = f2bf(v0.y); o[2] = f2bf(v0.z); o[3] = f2bf(v0.w);
  o[4] = f2bf(v1.x); o[5] = f2bf(v1.y); o[6] = f2bf(v1.z); o[7] = f2bf(v1.w);
  *(u16x8*)(zb + i * 8) = o;
}

// pos[row] = dot(z1[row], z2[row]) / TEMP in fp32 (full precision).
__global__ __launch_bounds__(256) void pos_kernel(
    const float* __restrict__ z1, const float* __restrict__ z2,
    float* __restrict__ pos) {
  int row = blockIdx.x, t = threadIdx.x;
  float4 a = ((const float4*)(z1 + (size_t)row * DIM))[t];
  float4 b = ((const float4*)(z2 + (size_t)row * DIM))[t];
  float s = a.x * b.x + a.y * b.y + a.z * b.z + a.w * b.w;
#pragma unroll
  for (int off = 1; off < 64; off <<= 1) s += __shfl_xor(s, off);
  __shared__ float tmp[4];
  if ((t & 63) == 0) tmp[t >> 6] = s;
  __syncthreads();
  if (t == 0) pos[row] = (tmp[0] + tmp[1] + tmp[2] + tmp[3]) * TEMP_INV;
}

// Main: 128x128 sim tile per block (upper triangle only), K=1024 via MFMA,
// epilogue exp + row/col sums -> atomicAdd into rowsum[8192].
__global__ __launch_bounds__(256) void lse_kernel(
    const unsigned short* __restrict__ zb, float* __restrict__ rowsum) {
  const int J = blockIdx.x, I = blockIdx.y;
  if (J < I) return;  // symmetry: upper-triangular tiles only

  __shared__ unsigned short sA[TILE * BK];  // [128][64] row-major
  __shared__ unsigned short sB[TILE * BK];
  const int t = threadIdx.x;
  const int wave = t >> 6, lane = t & 63;
  const int wr = wave >> 1, wc = wave & 1;  // 2x2 waves, each 64x64
  const int lo = lane & 15, hi = lane >> 4;

  f32x4 acc[4][4];
#pragma unroll
  for (int m = 0; m < 4; ++m)
#pragma unroll
    for (int n = 0; n < 4; ++n) acc[m][n] = (f32x4){0.f, 0.f, 0.f, 0.f};

  const int rowA0 = I * TILE;
  const int rowB0 = J * TILE;

  for (int kt = 0; kt < DIM / BK; ++kt) {
    // stage A,B tiles (128x64 bf16 each) via async global->LDS, 16B/lane
#pragma unroll
    for (int c = 0; c < 4; ++c) {
      int r = c * 32 + (t >> 3);
      const unsigned short* gA = zb + (size_t)(rowA0 + r) * DIM + kt * BK + (t & 7) * 8;
      const unsigned short* gB = zb + (size_t)(rowB0 + r) * DIM + kt * BK + (t & 7) * 8;
      unsigned short* lA = sA + c * 2048 + wave * 512;  // wave-uniform base
      unsigned short* lB = sB + c * 2048 + wave * 512;
      __builtin_amdgcn_global_load_lds((const __attribute__((address_space(1))) void*)gA,
                                       (__attribute__((address_space(3))) void*)lA, 16, 0, 0);
      __builtin_amdgcn_global_load_lds((const __attribute__((address_space(1))) void*)gB,
                                       (__attribute__((address_space(3))) void*)lB, 16, 0, 0);
    }
    __syncthreads();

#pragma unroll
    for (int kk = 0; kk < BK / 32; ++kk) {
      bf16x8 af[4], bg[4];
#pragma unroll
      for (int m = 0; m < 4; ++m)
        af[m] = *(const bf16x8*)(sA + (wr * 64 + m * 16 + lo) * BK + kk * 32 + hi * 8);
#pragma unroll
      for (int n = 0; n < 4; ++n)
        bg[n] = *(const bf16x8*)(sB + (wc * 64 + n * 16 + lo) * BK + kk * 32 + hi * 8);
#pragma unroll
      for (int m = 0; m < 4; ++m)
#pragma unroll
        for (int n = 0; n < 4; ++n)
          acc[m][n] = __builtin_amdgcn_mfma_f32_16x16x32_bf16(af[m], bg[n], acc[m][n], 0, 0, 0);
    }
    __syncthreads();
  }

  // Epilogue: e = exp((dot-1)/T), diag masked; row sums here, col sums
  // (= transpose contribution) for off-diagonal tiles.
  float csum[4] = {0.f, 0.f, 0.f, 0.f};
#pragma unroll
  for (int m = 0; m < 4; ++m) {
#pragma unroll
    for (int r = 0; r < 4; ++r) {
      const int grow = rowA0 + wr * 64 + m * 16 + hi * 4 + r;  // C/D: row=(lane>>4)*4+reg
      float s = 0.f;
#pragma unroll
      for (int n = 0; n < 4; ++n) {
        const int gcol = rowB0 + wc * 64 + n * 16 + lo;  // C/D: col=lane&15
        float e = exp2f((acc[m][n][r] - 1.0f) * EXP_SCALE);
        if (grow == gcol) e = 0.f;  // mask self-similarity
        s += e;
        csum[n] += e;
      }
      s += __shfl_xor(s, 1); s += __shfl_xor(s, 2);
      s += __shfl_xor(s, 4); s += __shfl_xor(s, 8);
      if (lo == 0) atomicAdd(&rowsum[grow], s);
    }
  }
  if (I != J) {
#pragma unroll
    for (int n = 0; n < 4; ++n) {
      float s = csum[n];
      s += __shfl_xor(s, 16); s += __shfl_xor(s, 32);
      if (hi == 0) atomicAdd(&rowsum[rowB0 + wc * 64 + n * 16 + lo], s);
    }
  }
}

__global__ __launch_bounds__(256) void finalize_kernel(
    const float* __restrict__ rowsum, const float* __restrict__ pos,
    float* __restrict__ out) {
  int t = threadIdx.x;
  float acc = 0.f;
  for (int i = t; i < TWO_N; i += 256)
    acc += TEMP_INV + logf(rowsum[i]) - pos[i & (NN - 1)];
#pragma unroll
  for (int off = 1; off < 64; off <<= 1) acc += __shfl_xor(acc, off);
  __shared__ float tmp[4];
  if ((t & 63) == 0) tmp[t >> 6] = acc;
  __syncthreads();
  if (t == 0) out[0] = (tmp[0] + tmp[1] + tmp[2] + tmp[3]) / (float)TWO_N;
}

extern "C" void kernel_launch(void* const* d_in, const int* in_sizes, int n_in,
                              void* d_out, int out_size, void* d_ws, size_t ws_size,
                              hipStream_t stream) {
  const float* z1 = (const float*)d_in[0];
  const float* z2 = (const float*)d_in[1];
  float* out = (float*)d_out;

  char* ws = (char*)d_ws;
  unsigned short* zb = (unsigned short*)ws;                       // 16 MB bf16 z
  float* rowsum = (float*)(ws + (size_t)TWO_N * DIM * 2);         // 32 KB
  float* pos = (float*)(ws + (size_t)TWO_N * DIM * 2 + TWO_N * 4);// 16 KB

  hipMemsetAsync(rowsum, 0, TWO_N * sizeof(float), stream);
  convert_kernel<<<TWO_N * DIM / 8 / 256, 256, 0, stream>>>(z1, z2, zb);
  pos_kernel<<<NN, 256, 0, stream>>>(z1, z2, pos);
  dim3 grid(TWO_N / TILE, TWO_N / TILE);
  lse_kernel<<<grid, 256, 0, stream>>>(zb, rowsum);
  finalize_kernel<<<1, 256, 0, stream>>>(rowsum, pos, out);
}

// Round 2
// 158.385 us; speedup vs baseline: 1.2912x; 1.2912x over previous
//
#include <hip/hip_runtime.h>
#include <hip/hip_bf16.h>

// InfoNCE loss, N=4096, D=1024, TEMP=0.07.
// loss = mean_i( -pos_i + lse_i ), lse over sim rows with diagonal masked.
// Fixed-max LSE (rows unit-norm -> sim <= 1/T): partials are order-independent
// -> atomicAdd across tiles, upper-triangular tiles only (symmetry).
//
// lse_kernel: 256x256 tile, 8 waves (2Mx4N), BK=32 ring-of-4 LDS slots,
// counted s_waitcnt vmcnt(12) (depth-3 prefetch, never drain-0 in loop),
// raw s_barrier, setprio around MFMA cluster, XOR-swizzled LDS reads with
// inverse-swizzled global_load_lds sources (linear LDS dest).

typedef __attribute__((ext_vector_type(8))) short bf16x8;
typedef __attribute__((ext_vector_type(4))) float f32x4;

#define NN 4096
#define TWO_N 8192
#define DIM 1024
#define TEMP_INV 14.285714285714286f
#define EXP_SCALE 20.609929155566303f /* log2(e)/0.07 */
#define NTILE 32  /* 8192/256 */
#define NBLK 528  /* 32*33/2 upper-tri tiles */

#define GLD16(g, l)                                                          \
  __builtin_amdgcn_global_load_lds(                                          \
      (const __attribute__((address_space(1))) void*)(g),                    \
      (__attribute__((address_space(3))) void*)(l), 16, 0, 0)

__device__ __forceinline__ unsigned short f2bf(float f) {
  unsigned int u = __float_as_uint(f);
  u += 0x7fffu + ((u >> 16) & 1u);  // RNE
  return (unsigned short)(u >> 16);
}

// Fused: fp32->bf16 cast of z=[z1;z2] AND pos[row]=dot(z1,z2)/T (one 32MB read).
__global__ __launch_bounds__(256) void prep_kernel(
    const float* __restrict__ z1, const float* __restrict__ z2,
    unsigned short* __restrict__ zb, float* __restrict__ pos) {
  const int row = blockIdx.x, t = threadIdx.x;
  float4 a = ((const float4*)(z1 + (size_t)row * DIM))[t];
  float4 b = ((const float4*)(z2 + (size_t)row * DIM))[t];
  ushort4 ua = {f2bf(a.x), f2bf(a.y), f2bf(a.z), f2bf(a.w)};
  ushort4 ub = {f2bf(b.x), f2bf(b.y), f2bf(b.z), f2bf(b.w)};
  ((ushort4*)(zb + (size_t)row * DIM))[t] = ua;
  ((ushort4*)(zb + (size_t)(NN + row) * DIM))[t] = ub;
  float s = a.x * b.x + a.y * b.y + a.z * b.z + a.w * b.w;
#pragma unroll
  for (int off = 1; off < 64; off <<= 1) s += __shfl_xor(s, off);
  __shared__ float tmp[4];
  if ((t & 63) == 0) tmp[t >> 6] = s;
  __syncthreads();
  if (t == 0) pos[row] = (tmp[0] + tmp[1] + tmp[2] + tmp[3]) * TEMP_INV;
}

__global__ __launch_bounds__(512, 2) void lse_kernel(
    const unsigned short* __restrict__ zb, float* __restrict__ rowsum) {
  extern __shared__ unsigned short lds[];  // 4 slots x (A 16KB + B 16KB) = 128 KiB
  // ---- tile decode: linear -> XCD-swizzled -> upper-tri (I<=J) ----
  int u = ((int)blockIdx.x & 7) * (NBLK / 8) + ((int)blockIdx.x >> 3);
  int I = 0, rem = u;
  while (rem >= NTILE - I) { rem -= NTILE - I; ++I; }
  const int J = I + rem;
  const int rowA0 = I * 256, rowB0 = J * 256;

  const int t = threadIdx.x;
  const int wave = t >> 6, lane = t & 63;
  const int wm = wave >> 2, wn = wave & 3;  // 2M x 4N waves, 128x64 out each
  const int lo = lane & 15, hi = lane >> 4;

  // ---- staging constants (thread t loads 4x16B per K-slot) ----
  // linear LDS layout per slot: A[256 rows][64B] then B[256][64B]; dest is
  // wave-uniform base + lane*16. Source pre-applies the inverse XOR swizzle:
  // phys 16B-group p at row r holds logical group p ^ ((r>>1)&3).
  const int srow = t >> 2;                           // row (l=0); +128 for l=1
  const int slog = (t & 3) ^ ((t >> 3) & 3);         // logical 8-elem group
  const size_t gA0 = (size_t)(rowA0 + srow) * DIM + slog * 8;
  const size_t gB0 = (size_t)(rowB0 + srow) * DIM + slog * 8;
  const int ldsw = wave * 512;  // wave-uniform (shorts): 1024B per wave

  // ---- compute-side ds_read offsets (shorts), swizzle applied on read ----
  const int sx = (hi ^ ((lo >> 1) & 3)) * 8;         // swizzled 16B group
  const int arow0 = wm * 128 + lo;                   // + m*16
  const int brow0 = wn * 64 + lo;                    // + n*16

  f32x4 acc[8][4];
#pragma unroll
  for (int m = 0; m < 8; ++m)
#pragma unroll
    for (int n = 0; n < 4; ++n) acc[m][n] = (f32x4){0.f, 0.f, 0.f, 0.f};

#define STAGE(kk_)                                                            \
  {                                                                           \
    const int k_ = (kk_);                                                     \
    unsigned short* sb = lds + (k_ & 3) * 16384;                              \
    const unsigned short* ga = zb + gA0 + (size_t)k_ * 32;                    \
    const unsigned short* gb = zb + gB0 + (size_t)k_ * 32;                    \
    GLD16(ga, sb + ldsw);                                                     \
    GLD16(ga + 128 * DIM, sb + 4096 + ldsw);                                  \
    GLD16(gb, sb + 8192 + ldsw);                                              \
    GLD16(gb + 128 * DIM, sb + 12288 + ldsw);                                 \
  }

  // prologue: fill 3 slots ahead
  STAGE(0); STAGE(1); STAGE(2);

  for (int s = 0; s < DIM / 32; ++s) {
    __builtin_amdgcn_s_barrier();          // everyone done reading slot s-1
    __builtin_amdgcn_sched_barrier(0);
    STAGE((s + 3) & 31);                   // wraps at tail: dummy re-stage, slots dead
    asm volatile("s_waitcnt vmcnt(12)" ::: "memory");  // slot-s loads landed
    __builtin_amdgcn_s_barrier();
    __builtin_amdgcn_sched_barrier(0);

    const unsigned short* slot = lds + (s & 3) * 16384;
    bf16x8 bg[4];
#pragma unroll
    for (int n = 0; n < 4; ++n)
      bg[n] = *(const bf16x8*)(slot + 8192 + (brow0 + n * 16) * 32 + sx);
    __builtin_amdgcn_s_setprio(1);
#pragma unroll
    for (int m = 0; m < 8; ++m) {
      bf16x8 af = *(const bf16x8*)(slot + (arow0 + m * 16) * 32 + sx);
#pragma unroll
      for (int n = 0; n < 4; ++n)
        acc[m][n] = __builtin_amdgcn_mfma_f32_16x16x32_bf16(af, bg[n], acc[m][n], 0, 0, 0);
    }
    __builtin_amdgcn_s_setprio(0);
  }
  asm volatile("s_waitcnt vmcnt(0)" ::: "memory");  // drain dangling tail stages

  // ---- epilogue: e=exp((dot-1)/T), diag masked; row sums + col sums ----
  float csum[4] = {0.f, 0.f, 0.f, 0.f};
#pragma unroll
  for (int m = 0; m < 8; ++m) {
#pragma unroll
    for (int r = 0; r < 4; ++r) {
      const int grow = rowA0 + wm * 128 + m * 16 + hi * 4 + r;  // row=(lane>>4)*4+reg
      float s = 0.f;
#pragma unroll
      for (int n = 0; n < 4; ++n) {
        const int gcol = rowB0 + wn * 64 + n * 16 + lo;         // col=lane&15
        float e = exp2f((acc[m][n][r] - 1.0f) * EXP_SCALE);
        if (grow == gcol) e = 0.f;  // mask self-similarity
        s += e;
        csum[n] += e;
      }
      s += __shfl_xor(s, 1); s += __shfl_xor(s, 2);
      s += __shfl_xor(s, 4); s += __shfl_xor(s, 8);
      if (lo == 0) atomicAdd(&rowsum[grow], s);
    }
  }
  if (I != J) {  // off-diagonal tiles feed the transposed rows via col sums
#pragma unroll
    for (int n = 0; n < 4; ++n) {
      float s = csum[n];
      s += __shfl_xor(s, 16); s += __shfl_xor(s, 32);
      if (hi == 0) atomicAdd(&rowsum[rowB0 + wn * 64 + n * 16 + lo], s);
    }
  }
#undef STAGE
}

__global__ __launch_bounds__(256) void finalize_kernel(
    const float* __restrict__ rowsum, const float* __restrict__ pos,
    float* __restrict__ out) {
  int t = threadIdx.x;
  float acc = 0.f;
  for (int i = t; i < TWO_N; i += 256)
    acc += TEMP_INV + logf(rowsum[i]) - pos[i & (NN - 1)];
#pragma unroll
  for (int off = 1; off < 64; off <<= 1) acc += __shfl_xor(acc, off);
  __shared__ float tmp[4];
  if ((t & 63) == 0) tmp[t >> 6] = acc;
  __syncthreads();
  if (t == 0) out[0] = (tmp[0] + tmp[1] + tmp[2] + tmp[3]) / (float)TWO_N;
}

extern "C" void kernel_launch(void* const* d_in, const int* in_sizes, int n_in,
                              void* d_out, int out_size, void* d_ws, size_t ws_size,
                              hipStream_t stream) {
  const float* z1 = (const float*)d_in[0];
  const float* z2 = (const float*)d_in[1];
  float* out = (float*)d_out;

  char* ws = (char*)d_ws;
  unsigned short* zb = (unsigned short*)ws;                        // 16 MB bf16 z
  float* rowsum = (float*)(ws + (size_t)TWO_N * DIM * 2);          // 32 KB
  float* pos = (float*)(ws + (size_t)TWO_N * DIM * 2 + TWO_N * 4); // 16 KB

  hipMemsetAsync(rowsum, 0, TWO_N * sizeof(float), stream);
  prep_kernel<<<NN, 256, 0, stream>>>(z1, z2, zb, pos);
  lse_kernel<<<NBLK, 512, 131072, stream>>>(zb, rowsum);
  finalize_kernel<<<1, 256, 0, stream>>>(rowsum, pos, out);
}

// Round 3
// 150.097 us; speedup vs baseline: 1.3625x; 1.0552x over previous
//
#include <hip/hip_runtime.h>
#include <hip/hip_bf16.h>

// InfoNCE loss, N=4096, D=1024, TEMP=0.07.
// loss = mean_i( -pos_i + lse_i ), lse over sim rows with diagonal masked.
// Fixed-max LSE (rows unit-norm -> sim <= 1/T): partials are order-independent
// -> atomicAdd across tiles, upper-triangular tiles only (symmetry).
//
// lse_kernel: 256x256 tile, 8 waves (2Mx4N), BK=32 ring-of-4 LDS slots,
// depth-3 prefetch with counted vmcnt(4), ONE raw s_barrier per K-step,
// register fragment double-buffer (read step s+1's fragments during step s's
// 32-MFMA cluster), setprio around MFMA, XOR-swizzled LDS reads with
// inverse-swizzled global_load_lds sources (linear LDS dest).

typedef __attribute__((ext_vector_type(8))) short bf16x8;
typedef __attribute__((ext_vector_type(4))) float f32x4;

#define NN 4096
#define TWO_N 8192
#define DIM 1024
#define TEMP_INV 14.285714285714286f
#define EXP_SCALE 20.609929155566303f /* log2(e)/0.07 */
#define NTILE 32  /* 8192/256 */
#define NBLK 528  /* 32*33/2 upper-tri tiles; 528 % 8 == 0 -> bijective swizzle */

#define GLD16(g, l)                                                          \
  __builtin_amdgcn_global_load_lds(                                          \
      (const __attribute__((address_space(1))) void*)(g),                    \
      (__attribute__((address_space(3))) void*)(l), 16, 0, 0)

__device__ __forceinline__ unsigned short f2bf(float f) {
  unsigned int u = __float_as_uint(f);
  u += 0x7fffu + ((u >> 16) & 1u);  // RNE
  return (unsigned short)(u >> 16);
}

// Fused: fp32->bf16 cast of z=[z1;z2] AND pos[row]=dot(z1,z2)/T (one 32MB read).
__global__ __launch_bounds__(256) void prep_kernel(
    const float* __restrict__ z1, const float* __restrict__ z2,
    unsigned short* __restrict__ zb, float* __restrict__ pos) {
  const int row = blockIdx.x, t = threadIdx.x;
  float4 a = ((const float4*)(z1 + (size_t)row * DIM))[t];
  float4 b = ((const float4*)(z2 + (size_t)row * DIM))[t];
  ushort4 ua = {f2bf(a.x), f2bf(a.y), f2bf(a.z), f2bf(a.w)};
  ushort4 ub = {f2bf(b.x), f2bf(b.y), f2bf(b.z), f2bf(b.w)};
  ((ushort4*)(zb + (size_t)row * DIM))[t] = ua;
  ((ushort4*)(zb + (size_t)(NN + row) * DIM))[t] = ub;
  float s = a.x * b.x + a.y * b.y + a.z * b.z + a.w * b.w;
#pragma unroll
  for (int off = 1; off < 64; off <<= 1) s += __shfl_xor(s, off);
  __shared__ float tmp[4];
  if ((t & 63) == 0) tmp[t >> 6] = s;
  __syncthreads();
  if (t == 0) pos[row] = (tmp[0] + tmp[1] + tmp[2] + tmp[3]) * TEMP_INV;
}

__global__ __launch_bounds__(512, 2) void lse_kernel(
    const unsigned short* __restrict__ zb, float* __restrict__ rowsum) {
  extern __shared__ unsigned short lds[];  // 4 slots x (A 16KB + B 16KB) = 128 KiB
  // ---- tile decode: linear -> XCD-swizzled -> upper-tri (I<=J) ----
  int u = ((int)blockIdx.x & 7) * (NBLK / 8) + ((int)blockIdx.x >> 3);
  int I = 0, rem = u;
  while (rem >= NTILE - I) { rem -= NTILE - I; ++I; }
  const int J = I + rem;
  const int rowA0 = I * 256, rowB0 = J * 256;

  const int t = threadIdx.x;
  const int wave = t >> 6, lane = t & 63;
  const int wm = wave >> 2, wn = wave & 3;  // 2M x 4N waves, 128x64 out each
  const int lo = lane & 15, hi = lane >> 4;

  // ---- staging constants (thread t loads 4x16B per K-slot) ----
  // linear LDS layout per slot: A rows [0,256) at r*32 shorts, B at 8192+r*32.
  // dest is wave-uniform base + lane*16. Source pre-applies the inverse XOR
  // swizzle: phys 16B-group p at row r holds logical group p ^ ((r>>1)&3).
  const int srow = t >> 2;                           // row (l=0); +128 for l=1
  const int slog = (t & 3) ^ ((t >> 3) & 3);         // logical 8-elem group
  const size_t gA0 = (size_t)(rowA0 + srow) * DIM + slog * 8;
  const size_t gB0 = (size_t)(rowB0 + srow) * DIM + slog * 8;
  const int ldsw = wave * 512;  // wave-uniform (shorts): 1024B per wave

  // ---- compute-side ds_read offsets (shorts), swizzle applied on read ----
  const int sx = (hi ^ ((lo >> 1) & 3)) * 8;         // swizzled 16B group
  const int arow0 = wm * 128 + lo;                   // + m*16
  const int brow0 = wn * 64 + lo;                    // + n*16

  f32x4 acc[8][4];
#pragma unroll
  for (int m = 0; m < 8; ++m)
#pragma unroll
    for (int n = 0; n < 4; ++n) acc[m][n] = (f32x4){0.f, 0.f, 0.f, 0.f};

#define STAGE(kk_)                                                            \
  {                                                                           \
    const int k_ = (kk_) & 31; /* gk wraps at tail; ring (kk_)&3 == k_&3 */   \
    unsigned short* sb = lds + (k_ & 3) * 16384;                              \
    const unsigned short* ga = zb + gA0 + (size_t)k_ * 32;                    \
    const unsigned short* gb = zb + gB0 + (size_t)k_ * 32;                    \
    GLD16(ga, sb + ldsw);                                                     \
    GLD16(ga + 128 * DIM, sb + 4096 + ldsw);                                  \
    GLD16(gb, sb + 8192 + ldsw);                                              \
    GLD16(gb + 128 * DIM, sb + 12288 + ldsw);                                 \
  }

#define READ_FRAGS(BG, AF, ring_)                                             \
  {                                                                           \
    const unsigned short* slot_ = lds + (ring_) * 16384;                      \
    _Pragma("unroll") for (int n = 0; n < 4; ++n)                             \
        BG[n] = *(const bf16x8*)(slot_ + 8192 + (brow0 + n * 16) * 32 + sx);  \
    _Pragma("unroll") for (int m = 0; m < 8; ++m)                             \
        AF[m] = *(const bf16x8*)(slot_ + (arow0 + m * 16) * 32 + sx);         \
  }

#define MFMA32(BG, AF)                                                        \
  __builtin_amdgcn_s_setprio(1);                                              \
  _Pragma("unroll") for (int m = 0; m < 8; ++m)                               \
    _Pragma("unroll") for (int n = 0; n < 4; ++n)                             \
        acc[m][n] = __builtin_amdgcn_mfma_f32_16x16x32_bf16(AF[m], BG[n],     \
                                                            acc[m][n], 0, 0, 0); \
  __builtin_amdgcn_s_setprio(0);

  // One K-step: wait slot s+1 landed (vmcnt: {s+1,s+2}=8 outstanding -> 4),
  // one barrier, stage slot s+3 (overwrites ring of s-1, whose frag reads
  // completed before the previous barrier), prefetch s+1 frags into the
  // alternate register set, run 32 MFMAs on the current set.
#define SUBSTEP(CBG, CAF, NBG, NAF, s_)                                       \
  asm volatile("s_waitcnt vmcnt(4)" ::: "memory");                            \
  __builtin_amdgcn_s_barrier();                                               \
  __builtin_amdgcn_sched_barrier(0);                                          \
  STAGE((s_) + 3);                                                            \
  READ_FRAGS(NBG, NAF, ((s_) + 1) & 3);                                       \
  MFMA32(CBG, CAF);                                                           \
  asm volatile("s_waitcnt lgkmcnt(0)" ::: "memory");                          \
  __builtin_amdgcn_sched_barrier(0);

  bf16x8 bgA[4], afA[8], bgB[4], afB[8];

  // prologue: fill 3 slots ahead, pre-read step-0 fragments
  STAGE(0); STAGE(1); STAGE(2);
  asm volatile("s_waitcnt vmcnt(8)" ::: "memory");  // slot 0 landed
  __builtin_amdgcn_s_barrier();
  __builtin_amdgcn_sched_barrier(0);
  READ_FRAGS(bgA, afA, 0);

#pragma unroll 1
  for (int it = 0; it < 16; ++it) {
    const int s0 = 2 * it;
    SUBSTEP(bgA, afA, bgB, afB, s0);
    SUBSTEP(bgB, afB, bgA, afA, s0 + 1);
  }
  asm volatile("s_waitcnt vmcnt(0)" ::: "memory");  // drain tail dummy stages

  // ---- epilogue: e=exp((dot-1)/T), diag masked; row sums + col sums ----
  float csum[4] = {0.f, 0.f, 0.f, 0.f};
#pragma unroll
  for (int m = 0; m < 8; ++m) {
#pragma unroll
    for (int r = 0; r < 4; ++r) {
      const int grow = rowA0 + wm * 128 + m * 16 + hi * 4 + r;  // row=(lane>>4)*4+reg
      float s = 0.f;
#pragma unroll
      for (int n = 0; n < 4; ++n) {
        const int gcol = rowB0 + wn * 64 + n * 16 + lo;         // col=lane&15
        float e = exp2f((acc[m][n][r] - 1.0f) * EXP_SCALE);
        if (grow == gcol) e = 0.f;  // mask self-similarity
        s += e;
        csum[n] += e;
      }
      s += __shfl_xor(s, 1); s += __shfl_xor(s, 2);
      s += __shfl_xor(s, 4); s += __shfl_xor(s, 8);
      if (lo == 0) atomicAdd(&rowsum[grow], s);
    }
  }
  if (I != J) {  // off-diagonal tiles feed the transposed rows via col sums
#pragma unroll
    for (int n = 0; n < 4; ++n) {
      float s = csum[n];
      s += __shfl_xor(s, 16); s += __shfl_xor(s, 32);
      if (hi == 0) atomicAdd(&rowsum[rowB0 + wn * 64 + n * 16 + lo], s);
    }
  }
#undef SUBSTEP
#undef MFMA32
#undef READ_FRAGS
#undef STAGE
}

__global__ __launch_bounds__(256) void finalize_kernel(
    const float* __restrict__ rowsum, const float* __restrict__ pos,
    float* __restrict__ out) {
  int t = threadIdx.x;
  float acc = 0.f;
  for (int i = t; i < TWO_N; i += 256)
    acc += TEMP_INV + logf(rowsum[i]) - pos[i & (NN - 1)];
#pragma unroll
  for (int off = 1; off < 64; off <<= 1) acc += __shfl_xor(acc, off);
  __shared__ float tmp[4];
  if ((t & 63) == 0) tmp[t >> 6] = acc;
  __syncthreads();
  if (t == 0) out[0] = (tmp[0] + tmp[1] + tmp[2] + tmp[3]) / (float)TWO_N;
}

extern "C" void kernel_launch(void* const* d_in, const int* in_sizes, int n_in,
                              void* d_out, int out_size, void* d_ws, size_t ws_size,
                              hipStream_t stream) {
  const float* z1 = (const float*)d_in[0];
  const float* z2 = (const float*)d_in[1];
  float* out = (float*)d_out;

  char* ws = (char*)d_ws;
  unsigned short* zb = (unsigned short*)ws;                        // 16 MB bf16 z
  float* rowsum = (float*)(ws + (size_t)TWO_N * DIM * 2);          // 32 KB
  float* pos = (float*)(ws + (size_t)TWO_N * DIM * 2 + TWO_N * 4); // 16 KB

  hipMemsetAsync(rowsum, 0, TWO_N * sizeof(float), stream);
  prep_kernel<<<NN, 256, 0, stream>>>(z1, z2, zb, pos);
  lse_kernel<<<NBLK, 512, 131072, stream>>>(zb, rowsum);
  finalize_kernel<<<1, 256, 0, stream>>>(rowsum, pos, out);
}

// Round 4
// 149.183 us; speedup vs baseline: 1.3709x; 1.0061x over previous
//
#include <hip/hip_runtime.h>
#include <hip/hip_bf16.h>

// InfoNCE loss, N=4096, D=1024, TEMP=0.07.
// loss = mean_i( -pos_i + lse_i ), lse over sim rows with diagonal masked.
// Fixed-max LSE (rows unit-norm -> sim <= 1/T): partials are order-independent
// -> atomicAdd across tiles, upper-triangular tiles only (symmetry).
//
// lse_kernel: 256x256 tile, 8 waves (2Mx4N), BK=32 ring-of-4 LDS slots,
// 8-phase-style schedule: each K-step = 2 phases x {half-stage, (gate),
// 6 ds_read for next step's frags, barrier, setprio + 16 MFMA, barrier}.
// Counted vmcnt(6) once per K-step (never 0 in loop). XOR-swizzled LDS
// reads with inverse-swizzled global_load_lds sources (linear LDS dest).

typedef __attribute__((ext_vector_type(8))) short bf16x8;
typedef __attribute__((ext_vector_type(4))) float f32x4;

#define NN 4096
#define TWO_N 8192
#define DIM 1024
#define TEMP_INV 14.285714285714286f
#define EXP_SCALE 20.609929155566303f /* log2(e)/0.07 */
#define NTILE 32  /* 8192/256 */
#define NBLK 528  /* 32*33/2 upper-tri tiles; 528 % 8 == 0 -> bijective swizzle */

#define GLD16(g, l)                                                          \
  __builtin_amdgcn_global_load_lds(                                          \
      (const __attribute__((address_space(1))) void*)(g),                    \
      (__attribute__((address_space(3))) void*)(l), 16, 0, 0)

__device__ __forceinline__ unsigned short f2bf(float f) {
  unsigned int u = __float_as_uint(f);
  u += 0x7fffu + ((u >> 16) & 1u);  // RNE
  return (unsigned short)(u >> 16);
}

// Fused: fp32->bf16 cast of z=[z1;z2] AND pos[row]=dot(z1,z2)/T (one 32MB read).
__global__ __launch_bounds__(256) void prep_kernel(
    const float* __restrict__ z1, const float* __restrict__ z2,
    unsigned short* __restrict__ zb, float* __restrict__ pos) {
  const int row = blockIdx.x, t = threadIdx.x;
  float4 a = ((const float4*)(z1 + (size_t)row * DIM))[t];
  float4 b = ((const float4*)(z2 + (size_t)row * DIM))[t];
  ushort4 ua = {f2bf(a.x), f2bf(a.y), f2bf(a.z), f2bf(a.w)};
  ushort4 ub = {f2bf(b.x), f2bf(b.y), f2bf(b.z), f2bf(b.w)};
  ((ushort4*)(zb + (size_t)row * DIM))[t] = ua;
  ((ushort4*)(zb + (size_t)(NN + row) * DIM))[t] = ub;
  float s = a.x * b.x + a.y * b.y + a.z * b.z + a.w * b.w;
#pragma unroll
  for (int off = 1; off < 64; off <<= 1) s += __shfl_xor(s, off);
  __shared__ float tmp[4];
  if ((t & 63) == 0) tmp[t >> 6] = s;
  __syncthreads();
  if (t == 0) pos[row] = (tmp[0] + tmp[1] + tmp[2] + tmp[3]) * TEMP_INV;
}

__global__ __launch_bounds__(512, 2) void lse_kernel(
    const unsigned short* __restrict__ zb, float* __restrict__ rowsum) {
  extern __shared__ unsigned short lds[];  // 4 slots x (A 16KB + B 16KB) = 128 KiB
  // ---- tile decode: linear -> XCD-swizzled -> upper-tri (I<=J) ----
  int u = ((int)blockIdx.x & 7) * (NBLK / 8) + ((int)blockIdx.x >> 3);
  int I = 0, rem = u;
  while (rem >= NTILE - I) { rem -= NTILE - I; ++I; }
  const int J = I + rem;
  const int rowA0 = I * 256, rowB0 = J * 256;

  const int t = threadIdx.x;
  const int wave = t >> 6, lane = t & 63;
  const int wm = wave >> 2, wn = wave & 3;  // 2M x 4N waves, 128x64 out each
  const int lo = lane & 15, hi = lane >> 4;

  // ---- staging constants (thread t loads 4x16B per K-slot, 2 per phase) ----
  // linear LDS layout per slot: A rows [0,256) at r*32 shorts, B at 8192+r*32.
  // dest is wave-uniform base + lane*16. Source pre-applies the inverse XOR
  // swizzle: phys 16B-group p at row r holds logical group p ^ ((r>>1)&3).
  const int srow = t >> 2;                           // row (l=0); +128 for l=1
  const int slog = (t & 3) ^ ((t >> 3) & 3);         // logical 8-elem group
  const size_t gA0 = (size_t)(rowA0 + srow) * DIM + slog * 8;
  const size_t gB0 = (size_t)(rowB0 + srow) * DIM + slog * 8;
  const int ldsw = wave * 512;  // wave-uniform (shorts): 1024B per wave

  // ---- compute-side ds_read offsets (shorts), swizzle applied on read ----
  const int sx = (hi ^ ((lo >> 1) & 3)) * 8;         // swizzled 16B group
  const int arow0 = wm * 128 + lo;                   // + m*16
  const int brow0 = wn * 64 + lo;                    // + n*16

  f32x4 acc[8][4];
#pragma unroll
  for (int m = 0; m < 8; ++m)
#pragma unroll
    for (int n = 0; n < 4; ++n) acc[m][n] = (f32x4){0.f, 0.f, 0.f, 0.f};

#define STAGE_A(kk_)                                                          \
  {                                                                           \
    const int k_ = (kk_) & 31; /* wraps at tail; ring (kk_)&3 == k_&3 */      \
    unsigned short* sb = lds + (k_ & 3) * 16384;                              \
    const unsigned short* ga = zb + gA0 + (size_t)k_ * 32;                    \
    GLD16(ga, sb + ldsw);                                                     \
    GLD16(ga + 128 * DIM, sb + 4096 + ldsw);                                  \
  }
#define STAGE_B(kk_)                                                          \
  {                                                                           \
    const int k_ = (kk_) & 31;                                                \
    unsigned short* sb = lds + (k_ & 3) * 16384;                              \
    const unsigned short* gb = zb + gB0 + (size_t)k_ * 32;                    \
    GLD16(gb, sb + 8192 + ldsw);                                              \
    GLD16(gb + 128 * DIM, sb + 12288 + ldsw);                                 \
  }

#define READ_A_LO(AF, ring_)                                                  \
  { const unsigned short* s_ = lds + (ring_) * 16384;                         \
    _Pragma("unroll") for (int m = 0; m < 4; ++m)                             \
      AF[m] = *(const bf16x8*)(s_ + (arow0 + m * 16) * 32 + sx); }
#define READ_A_HI(AF, ring_)                                                  \
  { const unsigned short* s_ = lds + (ring_) * 16384;                         \
    _Pragma("unroll") for (int m = 4; m < 8; ++m)                             \
      AF[m] = *(const bf16x8*)(s_ + (arow0 + m * 16) * 32 + sx); }
#define READ_B_LO(BG, ring_)                                                  \
  { const unsigned short* s_ = lds + (ring_) * 16384;                         \
    _Pragma("unroll") for (int n = 0; n < 2; ++n)                             \
      BG[n] = *(const bf16x8*)(s_ + 8192 + (brow0 + n * 16) * 32 + sx); }
#define READ_B_HI(BG, ring_)                                                  \
  { const unsigned short* s_ = lds + (ring_) * 16384;                         \
    _Pragma("unroll") for (int n = 2; n < 4; ++n)                             \
      BG[n] = *(const bf16x8*)(s_ + 8192 + (brow0 + n * 16) * 32 + sx); }

  // Phase A of step s: stage A(s+3) (pre-gate so it's counted in vmcnt),
  // gate slot s+1 ({A,B}(s+2)+A(s+3)=6 outstanding -> vmcnt(6)), barrier
  // publishes; read next-step LO frags; 16 MFMA on m0-3 of current.
#define PHASE_A(CA, CB, NA, NB, s_)                                           \
  STAGE_A((s_) + 3);                                                          \
  asm volatile("s_waitcnt vmcnt(6)" ::: "memory");                            \
  __builtin_amdgcn_s_barrier();                                               \
  READ_A_LO(NA, ((s_) + 1) & 3);                                              \
  READ_B_LO(NB, ((s_) + 1) & 3);                                              \
  __builtin_amdgcn_s_setprio(1);                                              \
  _Pragma("unroll") for (int m = 0; m < 4; ++m)                               \
    _Pragma("unroll") for (int n = 0; n < 4; ++n)                             \
      acc[m][n] = __builtin_amdgcn_mfma_f32_16x16x32_bf16(CA[m], CB[n],       \
                                                          acc[m][n], 0, 0, 0);\
  __builtin_amdgcn_s_setprio(0);                                              \
  __builtin_amdgcn_s_barrier();

  // Phase B of step s: stage B(s+3), read next-step HI frags, barrier,
  // 16 MFMA on m4-7 of current, barrier.
#define PHASE_B(CA, CB, NA, NB, s_)                                           \
  STAGE_B((s_) + 3);                                                          \
  READ_A_HI(NA, ((s_) + 1) & 3);                                              \
  READ_B_HI(NB, ((s_) + 1) & 3);                                              \
  __builtin_amdgcn_s_barrier();                                               \
  __builtin_amdgcn_s_setprio(1);                                              \
  _Pragma("unroll") for (int m = 4; m < 8; ++m)                               \
    _Pragma("unroll") for (int n = 0; n < 4; ++n)                             \
      acc[m][n] = __builtin_amdgcn_mfma_f32_16x16x32_bf16(CA[m], CB[n],       \
                                                          acc[m][n], 0, 0, 0);\
  __builtin_amdgcn_s_setprio(0);                                              \
  __builtin_amdgcn_s_barrier();

  bf16x8 afX[8], bgX[4], afY[8], bgY[4];

  // prologue: stage 3 slots ahead; gate slot 0 (8 newer loads outstanding);
  // read step-0 fragments.
  STAGE_A(0); STAGE_B(0); STAGE_A(1); STAGE_B(1); STAGE_A(2); STAGE_B(2);
  asm volatile("s_waitcnt vmcnt(8)" ::: "memory");
  __builtin_amdgcn_s_barrier();
  READ_A_LO(afX, 0); READ_B_LO(bgX, 0);
  READ_A_HI(afX, 0); READ_B_HI(bgX, 0);

#pragma unroll 1
  for (int it = 0; it < 16; ++it) {
    const int s0 = 2 * it;
    PHASE_A(afX, bgX, afY, bgY, s0);
    PHASE_B(afX, bgX, afY, bgY, s0);
    PHASE_A(afY, bgY, afX, bgX, s0 + 1);
    PHASE_B(afY, bgY, afX, bgX, s0 + 1);
  }
  asm volatile("s_waitcnt vmcnt(0)" ::: "memory");  // drain tail dummy stages

  // ---- epilogue: e=exp((dot-1)/T), diag masked; row sums + col sums ----
  float csum[4] = {0.f, 0.f, 0.f, 0.f};
#pragma unroll
  for (int m = 0; m < 8; ++m) {
#pragma unroll
    for (int r = 0; r < 4; ++r) {
      const int grow = rowA0 + wm * 128 + m * 16 + hi * 4 + r;  // row=(lane>>4)*4+reg
      float s = 0.f;
#pragma unroll
      for (int n = 0; n < 4; ++n) {
        const int gcol = rowB0 + wn * 64 + n * 16 + lo;         // col=lane&15
        float e = exp2f((acc[m][n][r] - 1.0f) * EXP_SCALE);
        if (grow == gcol) e = 0.f;  // mask self-similarity
        s += e;
        csum[n] += e;
      }
      s += __shfl_xor(s, 1); s += __shfl_xor(s, 2);
      s += __shfl_xor(s, 4); s += __shfl_xor(s, 8);
      if (lo == 0) atomicAdd(&rowsum[grow], s);
    }
  }
  if (I != J) {  // off-diagonal tiles feed the transposed rows via col sums
#pragma unroll
    for (int n = 0; n < 4; ++n) {
      float s = csum[n];
      s += __shfl_xor(s, 16); s += __shfl_xor(s, 32);
      if (hi == 0) atomicAdd(&rowsum[rowB0 + wn * 64 + n * 16 + lo], s);
    }
  }
#undef PHASE_A
#undef PHASE_B
#undef READ_A_LO
#undef READ_A_HI
#undef READ_B_LO
#undef READ_B_HI
#undef STAGE_A
#undef STAGE_B
}

__global__ __launch_bounds__(256) void finalize_kernel(
    const float* __restrict__ rowsum, const float* __restrict__ pos,
    float* __restrict__ out) {
  int t = threadIdx.x;
  float acc = 0.f;
  for (int i = t; i < TWO_N; i += 256)
    acc += TEMP_INV + logf(rowsum[i]) - pos[i & (NN - 1)];
#pragma unroll
  for (int off = 1; off < 64; off <<= 1) acc += __shfl_xor(acc, off);
  __shared__ float tmp[4];
  if ((t & 63) == 0) tmp[t >> 6] = acc;
  __syncthreads();
  if (t == 0) out[0] = (tmp[0] + tmp[1] + tmp[2] + tmp[3]) / (float)TWO_N;
}

extern "C" void kernel_launch(void* const* d_in, const int* in_sizes, int n_in,
                              void* d_out, int out_size, void* d_ws, size_t ws_size,
                              hipStream_t stream) {
  const float* z1 = (const float*)d_in[0];
  const float* z2 = (const float*)d_in[1];
  float* out = (float*)d_out;

  char* ws = (char*)d_ws;
  unsigned short* zb = (unsigned short*)ws;                        // 16 MB bf16 z
  float* rowsum = (float*)(ws + (size_t)TWO_N * DIM * 2);          // 32 KB
  float* pos = (float*)(ws + (size_t)TWO_N * DIM * 2 + TWO_N * 4); // 16 KB

  hipMemsetAsync(rowsum, 0, TWO_N * sizeof(float), stream);
  prep_kernel<<<NN, 256, 0, stream>>>(z1, z2, zb, pos);
  lse_kernel<<<NBLK, 512, 131072, stream>>>(zb, rowsum);
  finalize_kernel<<<1, 256, 0, stream>>>(rowsum, pos, out);
}

// Round 5
// 133.381 us; speedup vs baseline: 1.5333x; 1.1185x over previous
//
#include <hip/hip_runtime.h>
#include <hip/hip_bf16.h>

// InfoNCE loss, N=4096, D=1024, TEMP=0.07.
// loss = mean_i( -pos_i + lse_i ), lse over sim rows with diagonal masked.
// Fixed-max LSE (rows unit-norm -> sim <= 1/T): partials are order-independent
// -> atomicAdd across tiles; symmetry via 256x128 tiles with Jh >= 2I.
//
// lse_kernel: 256(M)x128(N) tile, 4 waves (2Mx2N, each 128x64 out), BK=32
// ring-of-3 LDS slots (72 KiB static -> 2 blocks/CU for cross-block latency
// hiding), depth-2 prefetch with counted vmcnt(6), one s_barrier per K-step,
// XOR-swizzled LDS reads with inverse-swizzled global_load_lds sources.

typedef __attribute__((ext_vector_type(8))) short bf16x8;
typedef __attribute__((ext_vector_type(4))) float f32x4;

#define NN 4096
#define TWO_N 8192
#define DIM 1024
#define TEMP_INV 14.285714285714286f
#define EXP_SCALE 20.609929155566303f /* log2(e)/0.07 */
#define NJT 64    /* N-tiles of 128 */
#define NBLK 1056 /* sum_I (64-2I), I=0..31; 1056 % 8 == 0 -> bijective swizzle */
#define SLOT 12288 /* shorts per slot: A 256x32 + B 128x32 */

#define GLD16(g, l)                                                          \
  __builtin_amdgcn_global_load_lds(                                          \
      (const __attribute__((address_space(1))) void*)(g),                    \
      (__attribute__((address_space(3))) void*)(l), 16, 0, 0)

__device__ __forceinline__ unsigned short f2bf(float f) {
  unsigned int u = __float_as_uint(f);
  u += 0x7fffu + ((u >> 16) & 1u);  // RNE
  return (unsigned short)(u >> 16);
}

// Fused: fp32->bf16 cast of z=[z1;z2] AND pos[row]=dot(z1,z2)/T (one 32MB read).
__global__ __launch_bounds__(256) void prep_kernel(
    const float* __restrict__ z1, const float* __restrict__ z2,
    unsigned short* __restrict__ zb, float* __restrict__ pos) {
  const int row = blockIdx.x, t = threadIdx.x;
  float4 a = ((const float4*)(z1 + (size_t)row * DIM))[t];
  float4 b = ((const float4*)(z2 + (size_t)row * DIM))[t];
  ushort4 ua = {f2bf(a.x), f2bf(a.y), f2bf(a.z), f2bf(a.w)};
  ushort4 ub = {f2bf(b.x), f2bf(b.y), f2bf(b.z), f2bf(b.w)};
  ((ushort4*)(zb + (size_t)row * DIM))[t] = ua;
  ((ushort4*)(zb + (size_t)(NN + row) * DIM))[t] = ub;
  float s = a.x * b.x + a.y * b.y + a.z * b.z + a.w * b.w;
#pragma unroll
  for (int off = 1; off < 64; off <<= 1) s += __shfl_xor(s, off);
  __shared__ float tmp[4];
  if ((t & 63) == 0) tmp[t >> 6] = s;
  __syncthreads();
  if (t == 0) pos[row] = (tmp[0] + tmp[1] + tmp[2] + tmp[3]) * TEMP_INV;
}

__global__ __launch_bounds__(256, 2) void lse_kernel(
    const unsigned short* __restrict__ zb, float* __restrict__ rowsum) {
  __shared__ unsigned short lds[3 * SLOT];  // 72 KiB -> 2 blocks/CU
  // ---- tile decode: XCD swizzle -> (I, Jh) with Jh >= 2I ----
  int u = ((int)blockIdx.x & 7) * (NBLK / 8) + ((int)blockIdx.x >> 3);
  int I = 0, rem = u;
  while (rem >= NJT - 2 * I) { rem -= NJT - 2 * I; ++I; }
  const int Jh = 2 * I + rem;
  const int rowA0 = I * 256, colB0 = Jh * 128;
  const bool straddle = (Jh >> 1) == I;  // tile lies within I's 256-block

  const int t = threadIdx.x;
  const int wave = t >> 6, lane = t & 63;
  const int wm = wave >> 1, wn = wave & 1;  // 2M x 2N waves, 128x64 out each
  const int lo = lane & 15, hi = lane >> 4;

  // ---- staging: per thread 4 A-chunks + 2 B-chunks (16B each) per slot ----
  // slot layout (shorts): A[256 rows][32] at 0, B[128][32] at 8192. Chunk c
  // (16B): row=c>>2, phys group p=c&3 holds logical lg = p ^ ((row>>1)&3)
  // (inverse of the read-side XOR). LDS dest = linear chunk order (wave-
  // uniform base; HW adds lane*16).
  int oA[4], oB[2];
  const int p = lane & 3;
#pragma unroll
  for (int i = 0; i < 4; ++i) {
    int c = (wave * 4 + i) * 64 + lane, row = c >> 2;
    oA[i] = (rowA0 + row) * DIM + (p ^ ((row >> 1) & 3)) * 8;
  }
#pragma unroll
  for (int i = 0; i < 2; ++i) {
    int c = (wave * 2 + i) * 64 + lane, row = c >> 2;
    oB[i] = (colB0 + row) * DIM + (p ^ ((row >> 1) & 3)) * 8;
  }

  // ---- compute-side ds_read offsets (shorts), swizzle applied on read ----
  const int sx = (hi ^ ((lo >> 1) & 3)) * 8;  // swizzled 16B group
  const int arow0 = wm * 128 + lo;            // + m*16
  const int brow0 = wn * 64 + lo;             // + n*16

  f32x4 acc[8][4];
#pragma unroll
  for (int m = 0; m < 8; ++m)
#pragma unroll
    for (int n = 0; n < 4; ++n) acc[m][n] = (f32x4){0.f, 0.f, 0.f, 0.f};

#define STAGE(dst_, k_)                                                       \
  {                                                                           \
    const unsigned short* gk = zb + (size_t)((k_) & 31) * 32;                 \
    GLD16(gk + oA[0], (dst_) + wave * 2048);                                  \
    GLD16(gk + oA[1], (dst_) + wave * 2048 + 512);                            \
    GLD16(gk + oA[2], (dst_) + wave * 2048 + 1024);                           \
    GLD16(gk + oA[3], (dst_) + wave * 2048 + 1536);                           \
    GLD16(gk + oB[0], (dst_) + 8192 + wave * 1024);                           \
    GLD16(gk + oB[1], (dst_) + 8192 + wave * 1024 + 512);                     \
  }

  unsigned short* s0 = lds;             // slot s (current)
  unsigned short* s1 = lds + SLOT;      // slot s+1
  unsigned short* s2 = lds + 2 * SLOT;  // slot s+2 (stage target)

  STAGE(s0, 0);
  STAGE(s1, 1);

#pragma unroll 1
  for (int s = 0; s < DIM / 32; ++s) {
    // gate: 6 newest (slot s+1) may stay in flight; slot s must be landed.
    asm volatile("s_waitcnt vmcnt(6)" ::: "memory");
    asm volatile("s_waitcnt lgkmcnt(0)" ::: "memory");  // prev frag reads done
    __builtin_amdgcn_s_barrier();  // publishes slot s; frees slot s-1 (=s2)
    __builtin_amdgcn_sched_barrier(0);
    STAGE(s2, s + 2);  // s>=30: dummy re-stage (k wraps), data never read

    bf16x8 bg[4];
#pragma unroll
    for (int n = 0; n < 4; ++n)
      bg[n] = *(const bf16x8*)(s0 + 8192 + (brow0 + n * 16) * 32 + sx);
    __builtin_amdgcn_s_setprio(1);
#pragma unroll
    for (int m = 0; m < 8; ++m) {
      bf16x8 af = *(const bf16x8*)(s0 + (arow0 + m * 16) * 32 + sx);
#pragma unroll
      for (int n = 0; n < 4; ++n)
        acc[m][n] = __builtin_amdgcn_mfma_f32_16x16x32_bf16(af, bg[n], acc[m][n], 0, 0, 0);
    }
    __builtin_amdgcn_s_setprio(0);
    unsigned short* tmp_ = s0; s0 = s1; s1 = s2; s2 = tmp_;  // rotate ring
  }
  asm volatile("s_waitcnt vmcnt(0) lgkmcnt(0)" ::: "memory");  // drain dummies

  // ---- epilogue: e=exp((dot-1)/T), diag masked; row sums + col sums ----
  float csum[4] = {0.f, 0.f, 0.f, 0.f};
#pragma unroll
  for (int m = 0; m < 8; ++m) {
#pragma unroll
    for (int r = 0; r < 4; ++r) {
      const int grow = rowA0 + wm * 128 + m * 16 + hi * 4 + r;  // row=(lane>>4)*4+reg
      float s = 0.f;
#pragma unroll
      for (int n = 0; n < 4; ++n) {
        const int gcol = colB0 + wn * 64 + n * 16 + lo;         // col=lane&15
        float e = exp2f((acc[m][n][r] - 1.0f) * EXP_SCALE);
        if (grow == gcol) e = 0.f;  // mask self-similarity (straddle tiles)
        s += e;
        csum[n] += e;
      }
      s += __shfl_xor(s, 1); s += __shfl_xor(s, 2);
      s += __shfl_xor(s, 4); s += __shfl_xor(s, 8);
      if (lo == 0) atomicAdd(&rowsum[grow], s);
    }
  }
  if (!straddle) {  // strictly-above tiles feed transposed rows via col sums
#pragma unroll
    for (int n = 0; n < 4; ++n) {
      float s = csum[n];
      s += __shfl_xor(s, 16); s += __shfl_xor(s, 32);
      if (hi == 0) atomicAdd(&rowsum[colB0 + wn * 64 + n * 16 + lo], s);
    }
  }
#undef STAGE
}

__global__ __launch_bounds__(256) void finalize_kernel(
    const float* __restrict__ rowsum, const float* __restrict__ pos,
    float* __restrict__ out) {
  int t = threadIdx.x;
  float acc = 0.f;
  for (int i = t; i < TWO_N; i += 256)
    acc += TEMP_INV + logf(rowsum[i]) - pos[i & (NN - 1)];
#pragma unroll
  for (int off = 1; off < 64; off <<= 1) acc += __shfl_xor(acc, off);
  __shared__ float tmp[4];
  if ((t & 63) == 0) tmp[t >> 6] = acc;
  __syncthreads();
  if (t == 0) out[0] = (tmp[0] + tmp[1] + tmp[2] + tmp[3]) / (float)TWO_N;
}

extern "C" void kernel_launch(void* const* d_in, const int* in_sizes, int n_in,
                              void* d_out, int out_size, void* d_ws, size_t ws_size,
                              hipStream_t stream) {
  const float* z1 = (const float*)d_in[0];
  const float* z2 = (const float*)d_in[1];
  float* out = (float*)d_out;

  char* ws = (char*)d_ws;
  unsigned short* zb = (unsigned short*)ws;                        // 16 MB bf16 z
  float* rowsum = (float*)(ws + (size_t)TWO_N * DIM * 2);          // 32 KB
  float* pos = (float*)(ws + (size_t)TWO_N * DIM * 2 + TWO_N * 4); // 16 KB

  hipMemsetAsync(rowsum, 0, TWO_N * sizeof(float), stream);
  prep_kernel<<<NN, 256, 0, stream>>>(z1, z2, zb, pos);
  lse_kernel<<<NBLK, 256, 0, stream>>>(zb, rowsum);
  finalize_kernel<<<1, 256, 0, stream>>>(rowsum, pos, out);
}